// Round 1
// 1104.645 us; speedup vs baseline: 1.3478x; 1.3478x over previous
//
#include <hip/hip_runtime.h>

typedef _Float16 half8 __attribute__((ext_vector_type(8)));
typedef _Float16 half4 __attribute__((ext_vector_type(4)));
typedef float floatx16 __attribute__((ext_vector_type(16)));

#define MFMA(a, b, c) __builtin_amdgcn_mfma_f32_32x32x16_f16(a, b, c, 0, 0, 0)

// Problem constants
#define NB   256
#define NF   512
#define NR   196
#define NI   1000
#define NV   300
#define IPAD 1024   // i padded to 1024 (16 tiles of 64)

// LDS strides (halves)
#define B1S   24    // stage-1 tile [196][24] (16 f + 8 pad) -- rows at 48B, 16B-aligned
#define BROWS 196
#define PS    200   // P [64][200]; rows at 400B, 16B-aligned; r>=196 zeroed

// -------------------- kernel 1: q = vecs @ w_g, split into fp16 hi/lo --------------------
__global__ __launch_bounds__(256) void qsplit_kernel(
    const float* __restrict__ vecs, const float* __restrict__ wg,
    _Float16* __restrict__ qh, _Float16* __restrict__ ql) {
    const int t = threadIdx.x;
    const int i0 = blockIdx.x * 8;
    __shared__ float vec[8][NV];
    for (int idx = t; idx < 8 * NV; idx += 256) {
        int ii = idx / NV;
        int v = idx - ii * NV;
        int i = i0 + ii;
        vec[ii][v] = (i < NI) ? vecs[(size_t)i * NV + v] : 0.0f;
    }
    __syncthreads();
    float acc[8][2];
#pragma unroll
    for (int ii = 0; ii < 8; ++ii) { acc[ii][0] = 0.f; acc[ii][1] = 0.f; }
#pragma unroll 4
    for (int v = 0; v < NV; ++v) {
        float w0 = wg[(size_t)v * NF + t];
        float w1 = wg[(size_t)v * NF + t + 256];
#pragma unroll
        for (int ii = 0; ii < 8; ++ii) {
            float x = vec[ii][v];
            acc[ii][0] += x * w0;
            acc[ii][1] += x * w1;
        }
    }
#pragma unroll
    for (int ii = 0; ii < 8; ++ii) {
        size_t i = i0 + ii;
        float q0 = acc[ii][0];
        float q1 = acc[ii][1];
        _Float16 h0 = (_Float16)q0;
        _Float16 h1 = (_Float16)q1;
        qh[i * NF + t]       = h0;
        qh[i * NF + t + 256] = h1;
        ql[i * NF + t]       = (_Float16)(q0 - (float)h0);
        ql[i * NF + t + 256] = (_Float16)(q1 - (float)h1);
    }
}

// -------------------- kernel 2: fused  S = q.h  -> softmax -> E = P.h^T --------------------
// grid (4096): XCD-swizzled so all 16 i-tiles of one b share an XCD L2.
// block = 256 (4 waves). wave w: mt = w>>1 (i rows 32*mt..+32), rh = w&1 (r-tiles).
__global__ __launch_bounds__(256, 2) void attn_kernel(
    const float* __restrict__ H, const _Float16* __restrict__ qh,
    const _Float16* __restrict__ ql, float* __restrict__ out) {
    __shared__ __align__(16) char smem[64256];
    _Float16* B0h = (_Float16*)smem;                 // [196][24] hi, buffer 0
    _Float16* B0l = (_Float16*)(smem + 9408);        // [196][24] lo, buffer 0
    _Float16* B1h = (_Float16*)(smem + 18816);       // [196][24] hi, buffer 1
    _Float16* B1l = (_Float16*)(smem + 28224);       // [196][24] lo, buffer 1
    _Float16* P   = (_Float16*)(smem + 37632);       // [64][200] softmax probs
    float* mp = (float*)(smem + 63232);              // [2][64] partial max
    float* lp = (float*)(smem + 63744);              // [2][64] partial sum

    const int tid  = threadIdx.x;
    const int lane = tid & 63;
    const int w    = tid >> 6;
    const int col  = lane & 31;   // n (r or f within 32-tile); also m for A-frags
    const int hf   = lane >> 5;   // k-half selector
    const int mt   = w >> 1;
    const int rh   = w & 1;
    const int t0   = rh * 4;
    const int ntile = rh ? 3 : 4;

    // XCD-aware swizzle: dispatch maps linear id n -> XCD n%8.
    // b = (n&7) + 8*(slot>>4) so the 16 i-tiles of b are n ≡ const (mod 8) -> same XCD.
    const int n      = blockIdx.x;
    const int xcd    = n & 7;
    const int slot   = n >> 3;
    const int b      = xcd + ((slot >> 4) << 3);
    const int i_base = (slot & 15) << 6;

    const float* Hb = H + (size_t)b * NF * NR;

    // staging geometry (loop-invariant per thread): 784 items = 4 fg-groups x 196 r
    int goff[4], loff[4];
    bool act[4];
#pragma unroll
    for (int s = 0; s < 4; ++s) {
        int idx = s * 256 + tid;
        act[s] = idx < 4 * NR;
        int ii = act[s] ? idx : 0;
        int fg = ii / NR;
        int r  = ii - fg * NR;
        goff[s] = fg * 4 * NR + r;
        loff[s] = r * B1S + fg * 4;
    }

    float4 sx[4];

#define LOADC(c_)                                                       \
    {                                                                   \
        const float* hc = Hb + (size_t)(c_) * (16 * NR);                \
        _Pragma("unroll")                                               \
        for (int s = 0; s < 4; ++s)                                     \
            if (act[s]) {                                               \
                const float* hp = hc + goff[s];                         \
                sx[s].x = hp[0];                                        \
                sx[s].y = hp[NR];                                       \
                sx[s].z = hp[2 * NR];                                   \
                sx[s].w = hp[3 * NR];                                   \
            }                                                           \
    }

#define CONVW(bh_, bl_)                                                 \
    {                                                                   \
        _Pragma("unroll")                                               \
        for (int s = 0; s < 4; ++s)                                     \
            if (act[s]) {                                               \
                float x0 = sx[s].x, x1 = sx[s].y, x2 = sx[s].z, x3 = sx[s].w; \
                _Float16 a0 = (_Float16)x0, a1 = (_Float16)x1;          \
                _Float16 a2 = (_Float16)x2, a3 = (_Float16)x3;          \
                half4 hi = {a0, a1, a2, a3};                            \
                half4 lo = {(_Float16)(x0 - (float)a0), (_Float16)(x1 - (float)a1), \
                            (_Float16)(x2 - (float)a2), (_Float16)(x3 - (float)a3)}; \
                *(half4*)&(bh_)[loff[s]] = hi;                          \
                *(half4*)&(bl_)[loff[s]] = lo;                          \
            }                                                           \
    }

    floatx16 acc[4];
#pragma unroll
    for (int t = 0; t < 4; ++t)
#pragma unroll
        for (int k = 0; k < 16; ++k) acc[t][k] = 0.0f;

    const size_t qoff = (size_t)(i_base + 32 * mt + col) * NF;

    // ---------------- stage 1: S = (qh+ql).(hh+hl), double-buffered, 1 barrier/iter --------
    LOADC(0);
    CONVW(B0h, B0l);

    for (int c = 0; c < 32; ++c) {
        __syncthreads();                 // buf[c&1] writes visible; prior reads of other buf done
        if (c < 31) LOADC(c + 1);        // issue next chunk's global loads (hidden under MFMAs)
        const _Float16* bh = (c & 1) ? B1h : B0h;
        const _Float16* bl = (c & 1) ? B1l : B0l;
        half8 a_h = *(const half8*)(qh + qoff + c * 16 + hf * 8);
        half8 a_l = *(const half8*)(ql + qoff + c * 16 + hf * 8);
#pragma unroll
        for (int t = 0; t < 4; ++t) {
            if (t < ntile) {
                int r  = (t0 + t) * 32 + col;
                int rb = r < BROWS ? r : BROWS - 1;  // rows>=196 are masked later; dup row 195
                half8 b_h = *(const half8*)&bh[rb * B1S + hf * 8];
                half8 b_l = *(const half8*)&bl[rb * B1S + hf * 8];
                acc[t] = MFMA(a_h, b_h, acc[t]);
                acc[t] = MFMA(a_l, b_h, acc[t]);
                acc[t] = MFMA(a_h, b_l, acc[t]);
            }
        }
        if (c < 31) {
            if (c & 1) { CONVW(B0h, B0l); } else { CONVW(B1h, B1l); }
        }
    }

    // ---------------- stage 2: softmax over r (split across rh wave pairs) ----------------
    float mx[16], sv[16];
#pragma unroll
    for (int j = 0; j < 16; ++j) {
        float m = -3.0e38f;
#pragma unroll
        for (int t = 0; t < 4; ++t) {
            if (t < ntile) {
                int r = (t0 + t) * 32 + col;
                float v = acc[t][j];
                if (r < NR) m = fmaxf(m, v);
            }
        }
#pragma unroll
        for (int s = 1; s < 32; s <<= 1) m = fmaxf(m, __shfl_xor(m, s));
        float l = 0.0f;
#pragma unroll
        for (int t = 0; t < 4; ++t) {
            if (t < ntile) {
                int r = (t0 + t) * 32 + col;
                if (r < NR) l += __expf(acc[t][j] - m);
            }
        }
#pragma unroll
        for (int s = 1; s < 32; s <<= 1) l += __shfl_xor(l, s);
        mx[j] = m;
        sv[j] = l;
    }
    if (col == 0) {
#pragma unroll
        for (int j = 0; j < 16; ++j) {
            int row = 32 * mt + (j & 3) + 8 * (j >> 2) + 4 * hf;
            mp[rh * 64 + row] = mx[j];
            lp[rh * 64 + row] = sv[j];
        }
    }
    __syncthreads();
#pragma unroll
    for (int j = 0; j < 16; ++j) {
        int row = 32 * mt + (j & 3) + 8 * (j >> 2) + 4 * hf;
        float m0 = mp[row], m1 = mp[64 + row];
        float l0 = lp[row], l1 = lp[64 + row];
        float M = fmaxf(m0, m1);
        float L = l0 * __expf(m0 - M) + l1 * __expf(m1 - M);
        float inv = 1.0f / L;
#pragma unroll
        for (int t = 0; t < 4; ++t) {
            if (t < ntile) {
                int r = (t0 + t) * 32 + col;
                if (r < PS) {
                    float p = (r < NR) ? __expf(acc[t][j] - M) * inv : 0.0f;
                    P[row * PS + r] = (_Float16)p;
                }
            }
        }
    }
    __syncthreads();   // P visible to all waves

    // ---------------- stage 3: E = P . h^T, B-frags direct from L2-hot global, 0 barriers ----
    const int myf  = rh * 32 + col;
    const int prow = (32 * mt + col) * PS;
    const size_t obase = ((size_t)b * NI + i_base) * NF;
#pragma unroll 1
    for (int fc = 0; fc < 8; ++fc) {
        const float* Hrow = Hb + (size_t)(fc * 64 + myf) * NR;
        floatx16 o0, o1;
#pragma unroll
        for (int k = 0; k < 16; ++k) { o0[k] = 0.0f; o1[k] = 0.0f; }
#pragma unroll
        for (int ks = 0; ks < 12; ++ks) {
            half8 a = *(const half8*)&P[prow + ks * 16 + hf * 8];
            const float* hp = Hrow + ks * 16 + hf * 8;
            float4 x0 = *(const float4*)hp;
            float4 x1 = *(const float4*)(hp + 4);
            half8 bb = {(_Float16)x0.x, (_Float16)x0.y, (_Float16)x0.z, (_Float16)x0.w,
                        (_Float16)x1.x, (_Float16)x1.y, (_Float16)x1.z, (_Float16)x1.w};
            if (ks & 1) o1 = MFMA(a, bb, o1);
            else        o0 = MFMA(a, bb, o0);
        }
        {   // ks = 12 tail: k = r in [192,208); r>=196 contributes zero (P is zero there)
            half8 a  = {(_Float16)0.f, (_Float16)0.f, (_Float16)0.f, (_Float16)0.f,
                        (_Float16)0.f, (_Float16)0.f, (_Float16)0.f, (_Float16)0.f};
            half8 bb = a;
            if (hf == 0) {
                a = *(const half8*)&P[prow + 192];
                float4 x0 = *(const float4*)(Hrow + 192);
                bb = (half8){(_Float16)x0.x, (_Float16)x0.y, (_Float16)x0.z, (_Float16)x0.w,
                             (_Float16)0.f, (_Float16)0.f, (_Float16)0.f, (_Float16)0.f};
            }
            o0 = MFMA(a, bb, o0);
        }
        const int f = fc * 64 + myf;
#pragma unroll
        for (int j = 0; j < 16; ++j) {
            int row = 32 * mt + (j & 3) + 8 * (j >> 2) + 4 * hf;
            if (i_base + row < NI) out[obase + (size_t)row * NF + f] = o0[j] + o1[j];
        }
    }
}

extern "C" void kernel_launch(void* const* d_in, const int* in_sizes, int n_in,
                              void* d_out, int out_size, void* d_ws, size_t ws_size,
                              hipStream_t stream) {
    const float* h_r  = (const float*)d_in[0];   // (256, 512, 196)
    const float* vecs = (const float*)d_in[1];   // (1000, 300)
    const float* w_g  = (const float*)d_in[2];   // (300, 512)
    float* out = (float*)d_out;                  // (256, 1000, 512) fp32

    _Float16* qh = (_Float16*)d_ws;              // [1024][512] fp16 hi
    _Float16* ql = qh + (size_t)IPAD * NF;       // [1024][512] fp16 lo

    hipLaunchKernelGGL(qsplit_kernel, dim3(128), dim3(256), 0, stream, vecs, w_g, qh, ql);
    hipLaunchKernelGGL(attn_kernel, dim3(4096), dim3(256), 0, stream, h_r, qh, ql, out);
}

// Round 2
// 1012.398 us; speedup vs baseline: 1.4706x; 1.0911x over previous
//
#include <hip/hip_runtime.h>

typedef _Float16 half8 __attribute__((ext_vector_type(8)));
typedef _Float16 half4 __attribute__((ext_vector_type(4)));
typedef float floatx16 __attribute__((ext_vector_type(16)));

#define MFMA(a, b, c) __builtin_amdgcn_mfma_f32_32x32x16_f16(a, b, c, 0, 0, 0)

// Problem constants
#define NB   256
#define NF   512
#define NR   196
#define NI   1000
#define NV   300
#define IPAD 1024   // i padded to 1024 (16 tiles of 64)

// LDS strides (halves)
#define B1S   24    // stage-1 tile [196][24] (16 f + 8 pad) -- rows at 48B, 16B-aligned
#define BROWS 196
#define PS    200   // P [64][200]; rows at 400B, 16B-aligned; r>=196 zeroed

// -------------------- kernel 1: q = vecs @ w_g, split into fp16 hi/lo --------------------
__global__ __launch_bounds__(256) void qsplit_kernel(
    const float* __restrict__ vecs, const float* __restrict__ wg,
    _Float16* __restrict__ qh, _Float16* __restrict__ ql) {
    const int t = threadIdx.x;
    const int i0 = blockIdx.x * 8;
    __shared__ float vec[8][NV];
    for (int idx = t; idx < 8 * NV; idx += 256) {
        int ii = idx / NV;
        int v = idx - ii * NV;
        int i = i0 + ii;
        vec[ii][v] = (i < NI) ? vecs[(size_t)i * NV + v] : 0.0f;
    }
    __syncthreads();
    float acc[8][2];
#pragma unroll
    for (int ii = 0; ii < 8; ++ii) { acc[ii][0] = 0.f; acc[ii][1] = 0.f; }
#pragma unroll 4
    for (int v = 0; v < NV; ++v) {
        float w0 = wg[(size_t)v * NF + t];
        float w1 = wg[(size_t)v * NF + t + 256];
#pragma unroll
        for (int ii = 0; ii < 8; ++ii) {
            float x = vec[ii][v];
            acc[ii][0] += x * w0;
            acc[ii][1] += x * w1;
        }
    }
#pragma unroll
    for (int ii = 0; ii < 8; ++ii) {
        size_t i = i0 + ii;
        float q0 = acc[ii][0];
        float q1 = acc[ii][1];
        _Float16 h0 = (_Float16)q0;
        _Float16 h1 = (_Float16)q1;
        qh[i * NF + t]       = h0;
        qh[i * NF + t + 256] = h1;
        ql[i * NF + t]       = (_Float16)(q0 - (float)h0);
        ql[i * NF + t + 256] = (_Float16)(q1 - (float)h1);
    }
}

// -------------------- kernel 2: fused  S = q.h  -> softmax -> E = P.h^T --------------------
// grid (4096): XCD-swizzled so all 16 i-tiles of one b share an XCD L2.
// block = 256 (4 waves). wave w: mt = w>>1 (i rows 32*mt..+32), rh = w&1 (r-tiles).
// LDS: stage-1 double buffers (37632 B) ALIASED with stage-2/3 P+mp/lp (26624 B) --
// disjoint in time, separated by a barrier after the stage-1 loop. 37632 B total
// -> 4 blocks/CU (was 2), doubling resident waves/SIMD for latency hiding.
__global__ __launch_bounds__(256, 4) void attn_kernel(
    const float* __restrict__ H, const _Float16* __restrict__ qh,
    const _Float16* __restrict__ ql, float* __restrict__ out) {
    __shared__ __align__(16) char smem[37632];
    _Float16* B0h = (_Float16*)smem;                 // [196][24] hi, buffer 0
    _Float16* B0l = (_Float16*)(smem + 9408);        // [196][24] lo, buffer 0
    _Float16* B1h = (_Float16*)(smem + 18816);       // [196][24] hi, buffer 1
    _Float16* B1l = (_Float16*)(smem + 28224);       // [196][24] lo, buffer 1
    _Float16* P   = (_Float16*)smem;                 // [64][200] softmax probs (aliases B0/B1)
    float* mp = (float*)(smem + 25600);              // [2][64] partial max
    float* lp = (float*)(smem + 26112);              // [2][64] partial sum

    const int tid  = threadIdx.x;
    const int lane = tid & 63;
    const int w    = tid >> 6;
    const int col  = lane & 31;   // n (r or f within 32-tile); also m for A-frags
    const int hf   = lane >> 5;   // k-half selector
    const int mt   = w >> 1;
    const int rh   = w & 1;
    const int t0   = rh * 4;
    const int ntile = rh ? 3 : 4;

    // XCD-aware swizzle: dispatch maps linear id n -> XCD n%8.
    // b = (n&7) + 8*(slot>>4) so the 16 i-tiles of b are n ≡ const (mod 8) -> same XCD.
    const int n      = blockIdx.x;
    const int xcd    = n & 7;
    const int slot   = n >> 3;
    const int b      = xcd + ((slot >> 4) << 3);
    const int i_base = (slot & 15) << 6;

    const float* Hb = H + (size_t)b * NF * NR;

    // staging geometry (loop-invariant per thread): 784 items = 4 fg-groups x 196 r
    int goff[4], loff[4];
    bool act[4];
#pragma unroll
    for (int s = 0; s < 4; ++s) {
        int idx = s * 256 + tid;
        act[s] = idx < 4 * NR;
        int ii = act[s] ? idx : 0;
        int fg = ii / NR;
        int r  = ii - fg * NR;
        goff[s] = fg * 4 * NR + r;
        loff[s] = r * B1S + fg * 4;
    }

    float4 sx[4];

#define LOADC(c_)                                                       \
    {                                                                   \
        const float* hc = Hb + (size_t)(c_) * (16 * NR);                \
        _Pragma("unroll")                                               \
        for (int s = 0; s < 4; ++s)                                     \
            if (act[s]) {                                               \
                const float* hp = hc + goff[s];                         \
                sx[s].x = hp[0];                                        \
                sx[s].y = hp[NR];                                       \
                sx[s].z = hp[2 * NR];                                   \
                sx[s].w = hp[3 * NR];                                   \
            }                                                           \
    }

#define CONVW(bh_, bl_)                                                 \
    {                                                                   \
        _Pragma("unroll")                                               \
        for (int s = 0; s < 4; ++s)                                     \
            if (act[s]) {                                               \
                float x0 = sx[s].x, x1 = sx[s].y, x2 = sx[s].z, x3 = sx[s].w; \
                _Float16 a0 = (_Float16)x0, a1 = (_Float16)x1;          \
                _Float16 a2 = (_Float16)x2, a3 = (_Float16)x3;          \
                half4 hi = {a0, a1, a2, a3};                            \
                half4 lo = {(_Float16)(x0 - (float)a0), (_Float16)(x1 - (float)a1), \
                            (_Float16)(x2 - (float)a2), (_Float16)(x3 - (float)a3)}; \
                *(half4*)&(bh_)[loff[s]] = hi;                          \
                *(half4*)&(bl_)[loff[s]] = lo;                          \
            }                                                           \
    }

    floatx16 acc[4];
#pragma unroll
    for (int t = 0; t < 4; ++t)
#pragma unroll
        for (int k = 0; k < 16; ++k) acc[t][k] = 0.0f;

    const size_t qoff = (size_t)(i_base + 32 * mt + col) * NF;

    // ---------------- stage 1: S = (qh+ql).(hh+hl), double-buffered, 1 barrier/iter --------
    LOADC(0);
    CONVW(B0h, B0l);

    for (int c = 0; c < 32; ++c) {
        __syncthreads();                 // buf[c&1] writes visible; prior reads of other buf done
        if (c < 31) LOADC(c + 1);        // issue next chunk's global loads (hidden under MFMAs)
        const _Float16* bh = (c & 1) ? B1h : B0h;
        const _Float16* bl = (c & 1) ? B1l : B0l;
        half8 a_h = *(const half8*)(qh + qoff + c * 16 + hf * 8);
        half8 a_l = *(const half8*)(ql + qoff + c * 16 + hf * 8);
#pragma unroll
        for (int t = 0; t < 4; ++t) {
            if (t < ntile) {
                int r  = (t0 + t) * 32 + col;
                int rb = r < BROWS ? r : BROWS - 1;  // rows>=196 are masked later; dup row 195
                half8 b_h = *(const half8*)&bh[rb * B1S + hf * 8];
                half8 b_l = *(const half8*)&bl[rb * B1S + hf * 8];
                acc[t] = MFMA(a_h, b_h, acc[t]);
                acc[t] = MFMA(a_l, b_h, acc[t]);
                acc[t] = MFMA(a_h, b_l, acc[t]);
            }
        }
        if (c < 31) {
            if (c & 1) { CONVW(B0h, B0l); } else { CONVW(B1h, B1l); }
        }
    }

    // P/mp/lp alias the B buffers: make sure every wave is done reading B1 before
    // any wave writes the aliased region.
    __syncthreads();

    // ---------------- stage 2: softmax over r (split across rh wave pairs) ----------------
    float mx[16], sv[16];
#pragma unroll
    for (int j = 0; j < 16; ++j) {
        float m = -3.0e38f;
#pragma unroll
        for (int t = 0; t < 4; ++t) {
            if (t < ntile) {
                int r = (t0 + t) * 32 + col;
                float v = acc[t][j];
                if (r < NR) m = fmaxf(m, v);
            }
        }
#pragma unroll
        for (int s = 1; s < 32; s <<= 1) m = fmaxf(m, __shfl_xor(m, s));
        float l = 0.0f;
#pragma unroll
        for (int t = 0; t < 4; ++t) {
            if (t < ntile) {
                int r = (t0 + t) * 32 + col;
                if (r < NR) l += __expf(acc[t][j] - m);
            }
        }
#pragma unroll
        for (int s = 1; s < 32; s <<= 1) l += __shfl_xor(l, s);
        mx[j] = m;
        sv[j] = l;
    }
    if (col == 0) {
#pragma unroll
        for (int j = 0; j < 16; ++j) {
            int row = 32 * mt + (j & 3) + 8 * (j >> 2) + 4 * hf;
            mp[rh * 64 + row] = mx[j];
            lp[rh * 64 + row] = sv[j];
        }
    }
    __syncthreads();
#pragma unroll
    for (int j = 0; j < 16; ++j) {
        int row = 32 * mt + (j & 3) + 8 * (j >> 2) + 4 * hf;
        float m0 = mp[row], m1 = mp[64 + row];
        float l0 = lp[row], l1 = lp[64 + row];
        float M = fmaxf(m0, m1);
        float L = l0 * __expf(m0 - M) + l1 * __expf(m1 - M);
        float inv = 1.0f / L;
#pragma unroll
        for (int t = 0; t < 4; ++t) {
            if (t < ntile) {
                int r = (t0 + t) * 32 + col;
                if (r < PS) {
                    float p = (r < NR) ? __expf(acc[t][j] - M) * inv : 0.0f;
                    P[row * PS + r] = (_Float16)p;
                }
            }
        }
    }
    __syncthreads();   // P visible to all waves

    // ---------------- stage 3: E = P . h^T, B-frags direct from L2-hot global, 0 barriers ----
    const int myf  = rh * 32 + col;
    const int prow = (32 * mt + col) * PS;
    const size_t obase = ((size_t)b * NI + i_base) * NF;
#pragma unroll 1
    for (int fc = 0; fc < 8; ++fc) {
        const float* Hrow = Hb + (size_t)(fc * 64 + myf) * NR;
        floatx16 o0, o1;
#pragma unroll
        for (int k = 0; k < 16; ++k) { o0[k] = 0.0f; o1[k] = 0.0f; }
#pragma unroll
        for (int ks = 0; ks < 12; ++ks) {
            half8 a = *(const half8*)&P[prow + ks * 16 + hf * 8];
            const float* hp = Hrow + ks * 16 + hf * 8;
            float4 x0 = *(const float4*)hp;
            float4 x1 = *(const float4*)(hp + 4);
            half8 bb = {(_Float16)x0.x, (_Float16)x0.y, (_Float16)x0.z, (_Float16)x0.w,
                        (_Float16)x1.x, (_Float16)x1.y, (_Float16)x1.z, (_Float16)x1.w};
            if (ks & 1) o1 = MFMA(a, bb, o1);
            else        o0 = MFMA(a, bb, o0);
        }
        {   // ks = 12 tail: k = r in [192,208); r>=196 contributes zero (P is zero there)
            half8 a  = {(_Float16)0.f, (_Float16)0.f, (_Float16)0.f, (_Float16)0.f,
                        (_Float16)0.f, (_Float16)0.f, (_Float16)0.f, (_Float16)0.f};
            half8 bb = a;
            if (hf == 0) {
                a = *(const half8*)&P[prow + 192];
                float4 x0 = *(const float4*)(Hrow + 192);
                bb = (half8){(_Float16)x0.x, (_Float16)x0.y, (_Float16)x0.z, (_Float16)x0.w,
                             (_Float16)0.f, (_Float16)0.f, (_Float16)0.f, (_Float16)0.f};
            }
            o0 = MFMA(a, bb, o0);
        }
        const int f = fc * 64 + myf;
#pragma unroll
        for (int j = 0; j < 16; ++j) {
            int row = 32 * mt + (j & 3) + 8 * (j >> 2) + 4 * hf;
            if (i_base + row < NI) out[obase + (size_t)row * NF + f] = o0[j] + o1[j];
        }
    }
}

extern "C" void kernel_launch(void* const* d_in, const int* in_sizes, int n_in,
                              void* d_out, int out_size, void* d_ws, size_t ws_size,
                              hipStream_t stream) {
    const float* h_r  = (const float*)d_in[0];   // (256, 512, 196)
    const float* vecs = (const float*)d_in[1];   // (1000, 300)
    const float* w_g  = (const float*)d_in[2];   // (300, 512)
    float* out = (float*)d_out;                  // (256, 1000, 512) fp32

    _Float16* qh = (_Float16*)d_ws;              // [1024][512] fp16 hi
    _Float16* ql = qh + (size_t)IPAD * NF;       // [1024][512] fp16 lo

    hipLaunchKernelGGL(qsplit_kernel, dim3(128), dim3(256), 0, stream, vecs, w_g, qh, ql);
    hipLaunchKernelGGL(attn_kernel, dim3(4096), dim3(256), 0, stream, h_r, qh, ql, out);
}